// Round 1
// baseline (1249.140 us; speedup 1.0000x reference)
//
#include <hip/hip_runtime.h>
#include <hip/hip_bf16.h>
#include <math.h>

// Problem constants (AttentionDecoder: B,C,H,W = 4,256,64,64)
#define BB 4
#define CC 256
#define C8 32
#define HH 64
#define WW 64
#define NN 4096   // HH*WW

static __device__ __forceinline__ float bf2f(unsigned short u) {
    union { unsigned int u; float f; } v; v.u = ((unsigned int)u) << 16;
    return v.f;
}
static __device__ __forceinline__ unsigned short f2bf(float f) {
    union { float f; unsigned int u; } v; v.f = f;
    return (unsigned short)((v.u + 0x7FFFu + ((v.u >> 16) & 1u)) >> 16);
}

// ---------------------------------------------------------------------------
// Kernel 1: Q and K projections (+ bias, + positional bias folded into K)
//   q[b][n][o]  = sum_c Wq[o][c] * x[b][c][n]  + bq[o]
//   kp[b][o][n] = sum_c Wk[o][c] * xe[b][c][n] + bk[o] + hp[o][n/64] + wp[o][n%64]
// grid: BB*(NN/64) blocks x 64 threads; thread owns one n.
// ---------------------------------------------------------------------------
__global__ __launch_bounds__(64) void qk_proj_kernel(
    const float* __restrict__ x, const float* __restrict__ xe,
    const float* __restrict__ Wq, const float* __restrict__ bq,
    const float* __restrict__ Wk, const float* __restrict__ bk,
    const float* __restrict__ hp, const float* __restrict__ wp,
    float* __restrict__ q, float* __restrict__ kp)
{
    const int nb = NN / 64;
    const int b  = blockIdx.x / nb;
    const int n  = (blockIdx.x % nb) * 64 + threadIdx.x;

    const float* xb  = x  + ((size_t)b * CC) * NN + n;
    const float* xeb = xe + ((size_t)b * CC) * NN + n;

    float qa[C8] = {}, ka[C8] = {};
    for (int c = 0; c < CC; ++c) {
        float xv  = xb[(size_t)c * NN];
        float xev = xeb[(size_t)c * NN];
        #pragma unroll
        for (int o = 0; o < C8; ++o) {
            qa[o] = fmaf(Wq[o * CC + c], xv,  qa[o]);
            ka[o] = fmaf(Wk[o * CC + c], xev, ka[o]);
        }
    }

    const int h = n >> 6, w = n & 63;
    float* qrow = q + ((size_t)b * NN + n) * C8;
    #pragma unroll
    for (int o = 0; o < C8; ++o) {
        qrow[o] = qa[o] + bq[o];
        kp[((size_t)b * C8 + o) * NN + n] = ka[o] + bk[o] + hp[o * HH + h] + wp[o * WW + w];
    }
}

// ---------------------------------------------------------------------------
// Kernel 2: V projection, stored transposed as bf16:
//   vt[b][n][c] = sum_k Wv[c][k] * xe[b][k][n] + bv[c]
// Tiled GEMM: 64(c) x 64(n) tile, 256 threads, 4x4 micro-tile per thread.
// grid: BB * (NN/64) * (CC/64) = 1024 blocks
// ---------------------------------------------------------------------------
__global__ __launch_bounds__(256) void v_proj_kernel(
    const float* __restrict__ xe, const float* __restrict__ Wv,
    const float* __restrict__ bv, unsigned short* __restrict__ vt)
{
    const int tilesN = NN / 64;   // 64
    const int tilesC = CC / 64;   // 4
    int blk = blockIdx.x;
    const int b = blk / (tilesN * tilesC);
    blk %= (tilesN * tilesC);
    const int n0 = (blk % tilesN) * 64;
    const int c0 = (blk / tilesN) * 64;

    const int t  = threadIdx.x;
    const int tx = t & 15;        // n-direction
    const int ty = t >> 4;        // c-direction

    __shared__ float Wt[16][64];  // [kk][cc]
    __shared__ float Xt[16][64];  // [kk][nn]

    float acc[4][4] = {};         // [c_sub][n_sub]

    for (int k0 = 0; k0 < CC; k0 += 16) {
        #pragma unroll
        for (int i = 0; i < 4; ++i) {
            int idx = t + i * 256;        // 0..1023
            int cc = idx >> 4, kk = idx & 15;
            Wt[kk][cc] = Wv[(size_t)(c0 + cc) * CC + k0 + kk];
        }
        #pragma unroll
        for (int i = 0; i < 4; ++i) {
            int idx = t + i * 256;
            int kk = idx >> 6, nn = idx & 63;
            Xt[kk][nn] = xe[((size_t)b * CC + k0 + kk) * NN + n0 + nn];
        }
        __syncthreads();

        #pragma unroll
        for (int kk = 0; kk < 16; ++kk) {
            float wr[4], xr[4];
            #pragma unroll
            for (int i = 0; i < 4; ++i) wr[i] = Wt[kk][ty * 4 + i];
            #pragma unroll
            for (int j = 0; j < 4; ++j) xr[j] = Xt[kk][tx * 4 + j];
            #pragma unroll
            for (int i = 0; i < 4; ++i)
                #pragma unroll
                for (int j = 0; j < 4; ++j)
                    acc[i][j] = fmaf(wr[i], xr[j], acc[i][j]);
        }
        __syncthreads();
    }

    // epilogue: add bias, store bf16 transposed [n][c]
    #pragma unroll
    for (int j = 0; j < 4; ++j) {
        int n = n0 + tx * 4 + j;
        ushort4 pk;
        pk.x = f2bf(acc[0][j] + bv[c0 + ty * 4 + 0]);
        pk.y = f2bf(acc[1][j] + bv[c0 + ty * 4 + 1]);
        pk.z = f2bf(acc[2][j] + bv[c0 + ty * 4 + 2]);
        pk.w = f2bf(acc[3][j] + bv[c0 + ty * 4 + 3]);
        *reinterpret_cast<ushort4*>(vt + ((size_t)b * NN + n) * CC + c0 + ty * 4) = pk;
    }
}

// ---------------------------------------------------------------------------
// Kernel 3: flash attention + fused epilogue  out = gamma * (P@V / l) + x
// Block: 16 query rows, 256 threads (4 waves). Key tiles of 64.
// Phase 1 (per wave: 4 rows):  e = q . kp, online softmax -> p in LDS
// Phase 2 (thread = 4 rows x 4 chans): acc = acc*alpha + p * vt
// grid: BB*(NN/16) = 1024 blocks
// ---------------------------------------------------------------------------
__global__ __launch_bounds__(256) void attn_kernel(
    const float* __restrict__ q, const float* __restrict__ kp,
    const unsigned short* __restrict__ vt, const float* __restrict__ x,
    const float* __restrict__ gamma, float* __restrict__ out)
{
    const int nb = NN / 16;       // 256 blocks per batch
    const int b  = blockIdx.x / nb;
    const int r0 = (blockIdx.x % nb) * 16;
    const int t    = threadIdx.x;
    const int wv   = t >> 6;      // wave 0..3
    const int lane = t & 63;

    __shared__ float qs[16][C8];
    __shared__ float p_lds[16][64];
    __shared__ float m_lds[16], l_lds[16], a_lds[16];

    {
        const float* qb = q + ((size_t)b * NN + r0) * C8;   // 512 floats
        for (int i = t; i < 16 * C8; i += 256)
            (&qs[0][0])[i] = qb[i];
    }
    if (t < 16) { m_lds[t] = -INFINITY; l_lds[t] = 0.f; }
    __syncthreads();

    const int rg = wv;            // phase-2 row group (= wave)
    const int cg = lane;          // phase-2 channel group
    float acc[4][4] = {};         // [row][chan]

    const float* kpb = kp + (size_t)b * C8 * NN;

    for (int m0 = 0; m0 < NN; m0 += 64) {
        // ---------- phase 1 ----------
        float e[4] = {0.f, 0.f, 0.f, 0.f};
        #pragma unroll
        for (int o = 0; o < C8; ++o) {
            float kvv = kpb[(size_t)o * NN + m0 + lane];
            #pragma unroll
            for (int rr = 0; rr < 4; ++rr)
                e[rr] = fmaf(qs[4 * wv + rr][o], kvv, e[rr]);
        }
        #pragma unroll
        for (int rr = 0; rr < 4; ++rr) {
            float tm = e[rr];
            #pragma unroll
            for (int s = 32; s > 0; s >>= 1)
                tm = fmaxf(tm, __shfl_xor(tm, s));
            const int r = 4 * wv + rr;
            float mo = m_lds[r];
            float mn = fmaxf(mo, tm);
            float al = __expf(mo - mn);
            float pv = __expf(e[rr] - mn);
            float rs = pv;
            #pragma unroll
            for (int s = 32; s > 0; s >>= 1)
                rs += __shfl_xor(rs, s);
            if (lane == 0) {
                l_lds[r] = l_lds[r] * al + rs;
                m_lds[r] = mn;
                a_lds[r] = al;
            }
            p_lds[r][lane] = pv;
        }
        __syncthreads();

        // ---------- phase 2 ----------
        float al4[4];
        #pragma unroll
        for (int i = 0; i < 4; ++i) al4[i] = a_lds[4 * rg + i];
        #pragma unroll
        for (int i = 0; i < 4; ++i)
            #pragma unroll
            for (int j = 0; j < 4; ++j)
                acc[i][j] *= al4[i];

        const unsigned short* vrow = vt + ((size_t)b * NN + m0) * CC + cg * 4;
        for (int mm = 0; mm < 64; ++mm) {
            ushort4 vx = *reinterpret_cast<const ushort4*>(vrow + (size_t)mm * CC);
            float v0 = bf2f(vx.x), v1 = bf2f(vx.y), v2 = bf2f(vx.z), v3 = bf2f(vx.w);
            #pragma unroll
            for (int i = 0; i < 4; ++i) {
                float pp = p_lds[4 * rg + i][mm];
                acc[i][0] = fmaf(pp, v0, acc[i][0]);
                acc[i][1] = fmaf(pp, v1, acc[i][1]);
                acc[i][2] = fmaf(pp, v2, acc[i][2]);
                acc[i][3] = fmaf(pp, v3, acc[i][3]);
            }
        }
        __syncthreads();
    }

    // ---------- epilogue: out = gamma*(acc/l) + x ----------
    const float g = gamma[0];
    float linv[4];
    #pragma unroll
    for (int i = 0; i < 4; ++i) linv[i] = 1.f / l_lds[4 * rg + i];

    #pragma unroll
    for (int j = 0; j < 4; ++j) {
        int c = cg * 4 + j;
        size_t idx = ((size_t)b * CC + c) * NN + r0 + 4 * rg;  // 4 consecutive n
        float4 xr = *reinterpret_cast<const float4*>(x + idx);
        float4 o4;
        o4.x = g * (acc[0][j] * linv[0]) + xr.x;
        o4.y = g * (acc[1][j] * linv[1]) + xr.y;
        o4.z = g * (acc[2][j] * linv[2]) + xr.z;
        o4.w = g * (acc[3][j] * linv[3]) + xr.w;
        *reinterpret_cast<float4*>(out + idx) = o4;
    }
}

// ---------------------------------------------------------------------------
extern "C" void kernel_launch(void* const* d_in, const int* in_sizes, int n_in,
                              void* d_out, int out_size, void* d_ws, size_t ws_size,
                              hipStream_t stream)
{
    (void)in_sizes; (void)n_in; (void)out_size; (void)ws_size;

    const float* x   = (const float*)d_in[0];
    const float* xe  = (const float*)d_in[1];
    const float* Wq  = (const float*)d_in[2];
    const float* bq  = (const float*)d_in[3];
    const float* Wk  = (const float*)d_in[4];
    const float* bk  = (const float*)d_in[5];
    const float* Wv  = (const float*)d_in[6];
    const float* bv  = (const float*)d_in[7];
    const float* hp  = (const float*)d_in[8];
    const float* wp  = (const float*)d_in[9];
    const float* gam = (const float*)d_in[10];
    float* out = (float*)d_out;

    // workspace layout (12.6 MB total):
    //   q  : f32 [B][N][C8]  = 2 MB
    //   kp : f32 [B][C8][N]  = 2 MB
    //   vt : bf16 [B][N][C]  = 8 MB
    char* ws = (char*)d_ws;
    float*          q  = (float*)ws;
    float*          kp = (float*)(ws + (size_t)BB * NN * C8 * 4);
    unsigned short* vt = (unsigned short*)(ws + 2 * (size_t)BB * NN * C8 * 4);

    qk_proj_kernel<<<BB * (NN / 64), 64, 0, stream>>>(x, xe, Wq, bq, Wk, bk, hp, wp, q, kp);
    v_proj_kernel<<<BB * (NN / 64) * (CC / 64), 256, 0, stream>>>(xe, Wv, bv, vt);
    attn_kernel<<<BB * (NN / 16), 256, 0, stream>>>(q, kp, vt, x, gam, out);
}

// Round 2
// 278.165 us; speedup vs baseline: 4.4906x; 4.4906x over previous
//
#include <hip/hip_runtime.h>
#include <hip/hip_bf16.h>
#include <math.h>

// Problem constants (AttentionDecoder: B,C,H,W = 4,256,64,64)
#define BB 4
#define CC 256
#define C8 32
#define HH 64
#define WW 64
#define NN 4096   // HH*WW
#define QBLK 64
#define KBLK 64

typedef __attribute__((ext_vector_type(8))) short bh8;   // 8 x bf16 (4 VGPR)
typedef __attribute__((ext_vector_type(4))) float f4;    // MFMA accumulator

static __device__ __forceinline__ float bf2f(unsigned short u) {
    union { unsigned int u; float f; } v; v.u = ((unsigned int)u) << 16;
    return v.f;
}
static __device__ __forceinline__ unsigned short f2bf(float f) {
    union { float f; unsigned int u; } v; v.f = f;
    return (unsigned short)((v.u + 0x7FFFu + ((v.u >> 16) & 1u)) >> 16);
}

// ---------------------------------------------------------------------------
// Kernel 1: Q/K projections -> bf16, pos folded into K.
//   qb[b][n][o] = sum_c Wq[o][c] x[b][c][n] + bq[o]
//   kb[b][n][o] = sum_c Wk[o][c] xe[b][c][n] + bk[o] + hp[o][h] + wp[o][w]
// block: 256 thr = 64 n x 4 o-groups (wave-uniform og -> W through s-loads)
// grid: B * N/64 = 256
// ---------------------------------------------------------------------------
__global__ __launch_bounds__(256) void qk_proj_kernel(
    const float* __restrict__ x, const float* __restrict__ xe,
    const float* __restrict__ Wq, const float* __restrict__ bq,
    const float* __restrict__ Wk, const float* __restrict__ bk,
    const float* __restrict__ hp, const float* __restrict__ wp,
    unsigned short* __restrict__ qb, unsigned short* __restrict__ kb)
{
    const int t  = threadIdx.x;
    const int b  = blockIdx.x >> 6;
    const int n  = ((blockIdx.x & 63) << 6) | (t & 63);
    const int og = t >> 6;            // 0..3, uniform per wave
    const int o0 = og * 8;

    const float* xp  = x  + (size_t)(b * CC) * NN + n;
    const float* xep = xe + (size_t)(b * CC) * NN + n;
    const float* wq  = Wq + (size_t)o0 * CC;
    const float* wk  = Wk + (size_t)o0 * CC;

    float qa[8] = {}, ka[8] = {};
    #pragma unroll 2
    for (int c = 0; c < CC; ++c) {
        float xv  = xp[(size_t)c * NN];
        float xev = xep[(size_t)c * NN];
        #pragma unroll
        for (int i = 0; i < 8; ++i) {
            qa[i] = fmaf(wq[i * CC + c], xv,  qa[i]);
            ka[i] = fmaf(wk[i * CC + c], xev, ka[i]);
        }
    }

    const int h = n >> 6, ww = n & 63;
    unsigned short qo[8], ko[8];
    #pragma unroll
    for (int i = 0; i < 8; ++i) {
        int o = o0 + i;
        qo[i] = f2bf(qa[i] + bq[o]);
        ko[i] = f2bf(ka[i] + bk[o] + hp[o * HH + h] + wp[o * WW + ww]);
    }
    size_t base = ((size_t)(b * NN) + n) * C8 + o0;   // 16B aligned
    *reinterpret_cast<uint4*>(qb + base) = *reinterpret_cast<const uint4*>(qo);
    *reinterpret_cast<uint4*>(kb + base) = *reinterpret_cast<const uint4*>(ko);
}

// ---------------------------------------------------------------------------
// Kernel 2: V projection -> bf16 natural layout v[b][c][n]
//   v[b][o][n] = sum_k Wv[o][k] xe[b][k][n] + bv[o]
// 64(c) x 64(n) tile, 256 threads, 4x4 micro-tile. grid: B*64*4 = 1024
// ---------------------------------------------------------------------------
__global__ __launch_bounds__(256) void v_proj_kernel(
    const float* __restrict__ xe, const float* __restrict__ Wv,
    const float* __restrict__ bv, unsigned short* __restrict__ v)
{
    const int tilesN = NN / 64;   // 64
    const int tilesC = CC / 64;   // 4
    int blk = blockIdx.x;
    const int b = blk / (tilesN * tilesC);
    blk %= (tilesN * tilesC);
    const int n0 = (blk % tilesN) * 64;
    const int c0 = (blk / tilesN) * 64;

    const int t  = threadIdx.x;
    const int tx = t & 15;        // n-direction
    const int ty = t >> 4;        // c-direction

    __shared__ float Wt[16][64];  // [kk][cc]
    __shared__ float Xt[16][64];  // [kk][nn]

    float acc[4][4] = {};         // [c_sub][n_sub]

    for (int k0 = 0; k0 < CC; k0 += 16) {
        #pragma unroll
        for (int i = 0; i < 4; ++i) {
            int idx = t + i * 256;
            int cc = idx >> 4, kk = idx & 15;
            Wt[kk][cc] = Wv[(size_t)(c0 + cc) * CC + k0 + kk];
        }
        #pragma unroll
        for (int i = 0; i < 4; ++i) {
            int idx = t + i * 256;
            int kk = idx >> 6, nn = idx & 63;
            Xt[kk][nn] = xe[((size_t)b * CC + k0 + kk) * NN + n0 + nn];
        }
        __syncthreads();

        #pragma unroll
        for (int kk = 0; kk < 16; ++kk) {
            float wr[4], xr[4];
            #pragma unroll
            for (int i = 0; i < 4; ++i) wr[i] = Wt[kk][ty * 4 + i];
            #pragma unroll
            for (int j = 0; j < 4; ++j) xr[j] = Xt[kk][tx * 4 + j];
            #pragma unroll
            for (int i = 0; i < 4; ++i)
                #pragma unroll
                for (int j = 0; j < 4; ++j)
                    acc[i][j] = fmaf(wr[i], xr[j], acc[i][j]);
        }
        __syncthreads();
    }

    // store bf16, natural [c][n] layout, coalesced along n
    #pragma unroll
    for (int i = 0; i < 4; ++i) {
        int c = c0 + ty * 4 + i;
        float bvv = bv[c];
        ushort4 pk;
        pk.x = f2bf(acc[i][0] + bvv);
        pk.y = f2bf(acc[i][1] + bvv);
        pk.z = f2bf(acc[i][2] + bvv);
        pk.w = f2bf(acc[i][3] + bvv);
        *reinterpret_cast<ushort4*>(v + ((size_t)(b * CC) + c) * NN + n0 + tx * 4) = pk;
    }
}

// ---------------------------------------------------------------------------
// Kernel 3: MFMA flash attention + fused epilogue  out = gamma*(P@V^T/l) + x
// 512 threads = 8 waves. QBLK=64 q-rows/block, KVBLK=64 keys/iter.
// QK^T: wave w computes S frags (qg in {2*(w>>2), +1}, ng = w&3) -> S_lds (f32, xor-swz)
// softmax: wave w owns rows w*8..w*8+7 (8 lanes/row), online m/l in regs,
//          P -> bf16 LDS (xor-swz, double buffered), alpha -> a_lds
// PV: wave w owns channels [w*32, w*32+32): 16 MFMAs/tile, acc 8 x f32x4
// grid: B * N/64 = 256 blocks; b = blockIdx&3 keeps batch per XCD-pair in L2
// ---------------------------------------------------------------------------
__global__ __launch_bounds__(512, 2) void attn_mfma_kernel(
    const unsigned short* __restrict__ qb, const unsigned short* __restrict__ kb,
    const unsigned short* __restrict__ v,  const float* __restrict__ x,
    const float* __restrict__ gamma, float* __restrict__ out)
{
    const int b   = blockIdx.x & 3;
    const int r0  = (blockIdx.x >> 2) << 6;     // q-tile base
    const int t   = threadIdx.x;
    const int w   = t >> 6;
    const int lane = t & 63;
    const int l15 = lane & 15, l4 = lane >> 4;  // l4: 0..3
    const int ng  = w & 3;
    const int qg0 = (w >> 2) * 2;               // 0 or 2

    __shared__ __align__(16) float S[64][64];             // 16 KB, col ^= 4*(q&7)
    __shared__ __align__(16) unsigned short P[2][64][64]; // 16 KB, col ^= 8*(q&7)
    __shared__ float a_lds[64];
    __shared__ float l_lds[64];

    // Q fragments (A-operand), held for whole kernel
    const bh8 qf0 = *reinterpret_cast<const bh8*>(
        qb + ((size_t)(b * NN) + r0 + qg0 * 16 + l15) * C8 + 8 * l4);
    const bh8 qf1 = *reinterpret_cast<const bh8*>(
        qb + ((size_t)(b * NN) + r0 + (qg0 + 1) * 16 + l15) * C8 + 8 * l4);

    // K pointer (B-operand, this wave's ng key-slice)
    const unsigned short* kptr = kb + ((size_t)(b * NN) + ng * 16 + l15) * C8 + 8 * l4;

    // V pointers [cgi][ks]: c = w*32 + cgi*16 + l15, key offset ks*32 + 8*l4
    const unsigned short* vp00 = v + ((size_t)(b * CC) + w * 32 + l15) * NN + 8 * l4;
    const unsigned short* vp01 = vp00 + 32;
    const unsigned short* vp10 = vp00 + 16 * NN;
    const unsigned short* vp11 = vp10 + 32;

    // softmax lane mapping: row srow, 8 lanes per row, 8 cols each
    const int srow  = w * 8 + (lane >> 3);
    const int sa    = lane & 7;
    const int scol0 = (8 * sa) ^ (4 * (srow & 7));
    float m_reg = -INFINITY, l_reg = 0.f;

    f4 acc[4][2] = {};   // [qgi][cgi]

    bh8 kf = *reinterpret_cast<const bh8*>(kptr);

    for (int tt = 0; tt < NN / KBLK; ++tt) {
        // ---- QK^T ----
        f4 z = {0.f, 0.f, 0.f, 0.f};
        f4 s0 = __builtin_amdgcn_mfma_f32_16x16x32_bf16(qf0, kf, z, 0, 0, 0);
        f4 s1 = __builtin_amdgcn_mfma_f32_16x16x32_bf16(qf1, kf, z, 0, 0, 0);
        kptr += KBLK * C8;
        bh8 kf_n = kf;
        if (tt < NN / KBLK - 1) kf_n = *reinterpret_cast<const bh8*>(kptr);

        #pragma unroll
        for (int r = 0; r < 4; ++r) {
            int q0 = qg0 * 16 + l4 * 4 + r;
            int q1 = q0 + 16;
            int kcol = ng * 16 + l15;
            S[q0][kcol ^ (4 * (q0 & 7))] = s0[r];
            S[q1][kcol ^ (4 * (q1 & 7))] = s1[r];
        }
        __syncthreads();   // b1: S complete

        // prefetch V for this tile (covered by softmax phase)
        bh8 vf00 = *reinterpret_cast<const bh8*>(vp00);
        bh8 vf01 = *reinterpret_cast<const bh8*>(vp01);
        bh8 vf10 = *reinterpret_cast<const bh8*>(vp10);
        bh8 vf11 = *reinterpret_cast<const bh8*>(vp11);
        vp00 += KBLK; vp01 += KBLK; vp10 += KBLK; vp11 += KBLK;

        // ---- online softmax (8 rows per wave) ----
        f4 sv0 = *reinterpret_cast<const f4*>(&S[srow][scol0]);
        f4 sv1 = *reinterpret_cast<const f4*>(&S[srow][scol0 ^ 4]);
        float tmax = fmaxf(fmaxf(fmaxf(sv0[0], sv0[1]), fmaxf(sv0[2], sv0[3])),
                           fmaxf(fmaxf(sv1[0], sv1[1]), fmaxf(sv1[2], sv1[3])));
        tmax = fmaxf(tmax, __shfl_xor(tmax, 1));
        tmax = fmaxf(tmax, __shfl_xor(tmax, 2));
        tmax = fmaxf(tmax, __shfl_xor(tmax, 4));
        float mn = fmaxf(m_reg, tmax);
        float alpha = __expf(m_reg - mn);
        float p0 = __expf(sv0[0] - mn), p1 = __expf(sv0[1] - mn);
        float p2 = __expf(sv0[2] - mn), p3 = __expf(sv0[3] - mn);
        float p4 = __expf(sv1[0] - mn), p5 = __expf(sv1[1] - mn);
        float p6 = __expf(sv1[2] - mn), p7 = __expf(sv1[3] - mn);
        float rs = ((p0 + p1) + (p2 + p3)) + ((p4 + p5) + (p6 + p7));
        rs += __shfl_xor(rs, 1);
        rs += __shfl_xor(rs, 2);
        rs += __shfl_xor(rs, 4);
        l_reg = l_reg * alpha + rs;
        m_reg = mn;
        if (sa == 0) a_lds[srow] = alpha;
        bh8 pb;
        pb[0] = (short)f2bf(p0); pb[1] = (short)f2bf(p1);
        pb[2] = (short)f2bf(p2); pb[3] = (short)f2bf(p3);
        pb[4] = (short)f2bf(p4); pb[5] = (short)f2bf(p5);
        pb[6] = (short)f2bf(p6); pb[7] = (short)f2bf(p7);
        *reinterpret_cast<bh8*>(&P[tt & 1][srow][(8 * sa) ^ (8 * (srow & 7))]) = pb;
        __syncthreads();   // b2: P + a_lds complete

        // ---- rescale + PV ----
        #pragma unroll
        for (int qgi = 0; qgi < 4; ++qgi) {
            f4 al = *reinterpret_cast<const f4*>(&a_lds[qgi * 16 + l4 * 4]);
            #pragma unroll
            for (int cgi = 0; cgi < 2; ++cgi) {
                acc[qgi][cgi][0] *= al[0];
                acc[qgi][cgi][1] *= al[1];
                acc[qgi][cgi][2] *= al[2];
                acc[qgi][cgi][3] *= al[3];
            }
        }
        const unsigned short* Pb = &P[tt & 1][0][0];
        #pragma unroll
        for (int ks = 0; ks < 2; ++ks) {
            bh8 pa[4];
            #pragma unroll
            for (int qgi = 0; qgi < 4; ++qgi) {
                int q   = qgi * 16 + l15;
                int col = (ks * 32 + 8 * l4) ^ (8 * (q & 7));
                pa[qgi] = *reinterpret_cast<const bh8*>(Pb + q * 64 + col);
            }
            bh8 vfa = ks ? vf01 : vf00;
            bh8 vfb = ks ? vf11 : vf10;
            #pragma unroll
            for (int qgi = 0; qgi < 4; ++qgi)
                acc[qgi][0] = __builtin_amdgcn_mfma_f32_16x16x32_bf16(pa[qgi], vfa, acc[qgi][0], 0, 0, 0);
            #pragma unroll
            for (int qgi = 0; qgi < 4; ++qgi)
                acc[qgi][1] = __builtin_amdgcn_mfma_f32_16x16x32_bf16(pa[qgi], vfb, acc[qgi][1], 0, 0, 0);
        }
        kf = kf_n;
        // no barrier needed: next S-write races nothing (S last read before b2;
        // P/a_lds reads of tile tt complete before b1 of tile tt+1)
    }

    // ---- epilogue: out = gamma*(acc/l) + x ----
    if (sa == 0) l_lds[srow] = l_reg;
    __syncthreads();
    const float g = gamma[0];
    #pragma unroll
    for (int qgi = 0; qgi < 4; ++qgi) {
        f4 lv = *reinterpret_cast<const f4*>(&l_lds[qgi * 16 + l4 * 4]);
        f4 li;
        li[0] = 1.f / lv[0]; li[1] = 1.f / lv[1];
        li[2] = 1.f / lv[2]; li[3] = 1.f / lv[3];
        #pragma unroll
        for (int cgi = 0; cgi < 2; ++cgi) {
            int c = w * 32 + cgi * 16 + l15;
            size_t idx = ((size_t)(b * CC) + c) * NN + r0 + qgi * 16 + l4 * 4;
            float4 xr = *reinterpret_cast<const float4*>(x + idx);
            float4 o4;
            o4.x = g * (acc[qgi][cgi][0] * li[0]) + xr.x;
            o4.y = g * (acc[qgi][cgi][1] * li[1]) + xr.y;
            o4.z = g * (acc[qgi][cgi][2] * li[2]) + xr.z;
            o4.w = g * (acc[qgi][cgi][3] * li[3]) + xr.w;
            *reinterpret_cast<float4*>(out + idx) = o4;
        }
    }
}

// ---------------------------------------------------------------------------
extern "C" void kernel_launch(void* const* d_in, const int* in_sizes, int n_in,
                              void* d_out, int out_size, void* d_ws, size_t ws_size,
                              hipStream_t stream)
{
    (void)in_sizes; (void)n_in; (void)out_size; (void)ws_size;

    const float* x   = (const float*)d_in[0];
    const float* xe  = (const float*)d_in[1];
    const float* Wq  = (const float*)d_in[2];
    const float* bq  = (const float*)d_in[3];
    const float* Wk  = (const float*)d_in[4];
    const float* bk  = (const float*)d_in[5];
    const float* Wv  = (const float*)d_in[6];
    const float* bv  = (const float*)d_in[7];
    const float* hp  = (const float*)d_in[8];
    const float* wp  = (const float*)d_in[9];
    const float* gam = (const float*)d_in[10];
    float* out = (float*)d_out;

    // workspace: qb bf16 [B][N][32] (1MB) | kb bf16 [B][N][32] (1MB) | v bf16 [B][C][N] (8MB)
    char* ws = (char*)d_ws;
    unsigned short* qb = (unsigned short*)ws;
    unsigned short* kb = (unsigned short*)(ws + (size_t)BB * NN * C8 * 2);
    unsigned short* v  = (unsigned short*)(ws + 2 * (size_t)BB * NN * C8 * 2);

    qk_proj_kernel<<<BB * (NN / 64), 256, 0, stream>>>(x, xe, Wq, bq, Wk, bk, hp, wp, qb, kb);
    v_proj_kernel<<<BB * (NN / 64) * (CC / 64), 256, 0, stream>>>(xe, Wv, bv, v);
    attn_mfma_kernel<<<BB * (NN / QBLK), 512, 0, stream>>>(qb, kb, v, x, gam, out);
}

// Round 3
// 119.848 us; speedup vs baseline: 10.4227x; 2.3210x over previous
//
#include <hip/hip_runtime.h>
#include <hip/hip_bf16.h>
#include <math.h>

// Problem constants (AttentionDecoder: B,C,H,W = 4,256,64,64)
#define BB 4
#define CC 256
#define C8 32
#define HH 64
#define WW 64
#define NN 4096   // HH*WW
#define QBLK 64
#define KBLK 64

typedef __attribute__((ext_vector_type(8))) short bh8;   // 8 x bf16 (4 VGPR)
typedef __attribute__((ext_vector_type(4))) float f4;    // MFMA accumulator

static __device__ __forceinline__ float bf2f(unsigned short u) {
    union { unsigned int u; float f; } v; v.u = ((unsigned int)u) << 16;
    return v.f;
}
static __device__ __forceinline__ unsigned short f2bf(float f) {
    union { float f; unsigned int u; } v; v.f = f;
    return (unsigned short)((v.u + 0x7FFFu + ((v.u >> 16) & 1u)) >> 16);
}

// ---------------------------------------------------------------------------
// Kernel 0: pack [Wq;Wk;Wv] -> bf16 wb[320][256]
// rows 0-31 = Wq, 32-63 = Wk, 64-319 = Wv. grid 80 x 256 (20480 float4s)
// ---------------------------------------------------------------------------
__global__ __launch_bounds__(256) void wconv_kernel(
    const float* __restrict__ Wq, const float* __restrict__ Wk,
    const float* __restrict__ Wv, unsigned short* __restrict__ wb)
{
    int f = (blockIdx.x * 256 + threadIdx.x) * 4;   // element index, < 81920
    const float* src;
    if (f < 32 * 256)           src = Wq + f;
    else if (f < 64 * 256)      src = Wk + (f - 32 * 256);
    else                        src = Wv + (f - 64 * 256);
    float4 v = *reinterpret_cast<const float4*>(src);
    ushort4 o;
    o.x = f2bf(v.x); o.y = f2bf(v.y); o.z = f2bf(v.z); o.w = f2bf(v.w);
    *reinterpret_cast<ushort4*>(wb + f) = o;
}

// ---------------------------------------------------------------------------
// Kernel 1: fused Q/K/V projection GEMM (MFMA).
// OUT[o][n] = sum_c W[o][c] * X[c][n];  o in [0,320): 0-31 Q(x), 32-63 K(xe),
// 64-319 V(xe). Per block: n-tile of 64, all 320 rows, K=256 full.
// 640 thr = 10 waves; wave w owns rows [w*32, w*32+32).
// Staging: x/xe [256c][64n] f32 -> bf16 transposed LDS xT[n][c], c ^= (n&7)<<3.
// Outputs: qb[n][32], kb[n][32] (+bias+pos), v[c][n] (+bias) -- attn layouts.
// grid: B * N/64 = 256
// ---------------------------------------------------------------------------
__global__ __launch_bounds__(640, 1) void proj_kernel(
    const float* __restrict__ x, const float* __restrict__ xe,
    const unsigned short* __restrict__ wb,
    const float* __restrict__ bq, const float* __restrict__ bk,
    const float* __restrict__ bv,
    const float* __restrict__ hp, const float* __restrict__ wp,
    unsigned short* __restrict__ qb, unsigned short* __restrict__ kb,
    unsigned short* __restrict__ vv)
{
    const int b  = blockIdx.x & 3;
    const int n0 = (blockIdx.x >> 2) << 6;
    const int t  = threadIdx.x;
    const int w  = t >> 6;                 // 0..9
    const int lane = t & 63;
    const int l15 = lane & 15, l4 = lane >> 4;

    __shared__ unsigned short xT[64][256];   // [n][c^swz]  32 KB
    __shared__ unsigned short xeT[64][256];  // 32 KB

    // ---- load A fragments (weights, L2-resident) ----
    bh8 af[2][8];
    {
        const unsigned short* wrow = wb + (size_t)(w * 32 + l15) * 256 + l4 * 8;
        #pragma unroll
        for (int kk = 0; kk < 8; ++kk) {
            af[0][kk] = *reinterpret_cast<const bh8*>(wrow + kk * 32);
            af[1][kk] = *reinterpret_cast<const bh8*>(wrow + 16 * 256 + kk * 32);
        }
    }

    // ---- stage + transpose + convert ----
    {
        const float* xb  = x  + (size_t)(b * CC) * NN + n0;
        const float* xeb = xe + (size_t)(b * CC) * NN + n0;
        for (int i = t; i < 4096; i += 640) {
            int c = i >> 4, n4 = (i & 15) << 2;
            float4 a = *reinterpret_cast<const float4*>(xb  + (size_t)c * NN + n4);
            float4 e = *reinterpret_cast<const float4*>(xeb + (size_t)c * NN + n4);
            #pragma unroll
            for (int j = 0; j < 4; ++j) {
                int n  = n4 + j;
                int cs = c ^ ((n & 7) << 3);
                xT[n][cs]  = f2bf((&a.x)[j]);
                xeT[n][cs] = f2bf((&e.x)[j]);
            }
        }
    }
    __syncthreads();

    // ---- MFMA main: acc[mf][nf] over 8 k-steps ----
    const unsigned short* lds = (w == 0) ? &xT[0][0] : &xeT[0][0];
    f4 acc[2][4] = {};
    #pragma unroll
    for (int kk = 0; kk < 8; ++kk) {
        bh8 bf[4];
        #pragma unroll
        for (int nf = 0; nf < 4; ++nf) {
            int n  = nf * 16 + l15;
            int c0 = (kk * 32 + l4 * 8) ^ ((n & 7) << 3);
            bf[nf] = *reinterpret_cast<const bh8*>(lds + n * 256 + c0);
        }
        #pragma unroll
        for (int nf = 0; nf < 4; ++nf) {
            acc[0][nf] = __builtin_amdgcn_mfma_f32_16x16x32_bf16(af[0][kk], bf[nf], acc[0][nf], 0, 0, 0);
            acc[1][nf] = __builtin_amdgcn_mfma_f32_16x16x32_bf16(af[1][kk], bf[nf], acc[1][nf], 0, 0, 0);
        }
    }

    // ---- epilogue ----
    if (w < 2) {
        // Q (w=0) / K (w=1): out [n][32]; D row = o = mf*16 + l4*4 + r
        unsigned short* dst = (w == 0 ? qb : kb) + (size_t)(b * NN) * C8;
        const float* bias = (w == 0) ? bq : bk;
        #pragma unroll
        for (int mf = 0; mf < 2; ++mf) {
            #pragma unroll
            for (int nf = 0; nf < 4; ++nf) {
                int n  = n0 + nf * 16 + l15;
                int oo = mf * 16 + l4 * 4;
                ushort4 pk;
                #pragma unroll
                for (int r = 0; r < 4; ++r) {
                    int o = oo + r;
                    float val = acc[mf][nf][r] + bias[o];
                    if (w == 1) val += hp[o * HH + (n >> 6)] + wp[o * WW + (n & 63)];
                    (&pk.x)[r] = f2bf(val);
                }
                *reinterpret_cast<ushort4*>(dst + (size_t)n * C8 + oo) = pk;
            }
        }
    } else {
        // V: c = (w-2)*32 + mf*16 + l4*4 + r; out v[c][n]
        #pragma unroll
        for (int mf = 0; mf < 2; ++mf) {
            int cb = (w - 2) * 32 + mf * 16 + l4 * 4;
            #pragma unroll
            for (int r = 0; r < 4; ++r) {
                float bvv = bv[cb + r];
                #pragma unroll
                for (int nf = 0; nf < 4; ++nf) {
                    int n = n0 + nf * 16 + l15;
                    vv[(size_t)(b * CC + cb + r) * NN + n] = f2bf(acc[mf][nf][r] + bvv);
                }
            }
        }
    }
}

// ---------------------------------------------------------------------------
// Kernel 2: MFMA flash attention + fused epilogue  out = gamma*(P@V^T/l) + x
// (unchanged from round 2)
// ---------------------------------------------------------------------------
__global__ __launch_bounds__(512, 2) void attn_mfma_kernel(
    const unsigned short* __restrict__ qb, const unsigned short* __restrict__ kb,
    const unsigned short* __restrict__ v,  const float* __restrict__ x,
    const float* __restrict__ gamma, float* __restrict__ out)
{
    const int b   = blockIdx.x & 3;
    const int r0  = (blockIdx.x >> 2) << 6;     // q-tile base
    const int t   = threadIdx.x;
    const int w   = t >> 6;
    const int lane = t & 63;
    const int l15 = lane & 15, l4 = lane >> 4;  // l4: 0..3
    const int ng  = w & 3;
    const int qg0 = (w >> 2) * 2;               // 0 or 2

    __shared__ __align__(16) float S[64][64];             // 16 KB, col ^= 4*(q&7)
    __shared__ __align__(16) unsigned short P[2][64][64]; // 16 KB, col ^= 8*(q&7)
    __shared__ float a_lds[64];
    __shared__ float l_lds[64];

    const bh8 qf0 = *reinterpret_cast<const bh8*>(
        qb + ((size_t)(b * NN) + r0 + qg0 * 16 + l15) * C8 + 8 * l4);
    const bh8 qf1 = *reinterpret_cast<const bh8*>(
        qb + ((size_t)(b * NN) + r0 + (qg0 + 1) * 16 + l15) * C8 + 8 * l4);

    const unsigned short* kptr = kb + ((size_t)(b * NN) + ng * 16 + l15) * C8 + 8 * l4;

    const unsigned short* vp00 = v + ((size_t)(b * CC) + w * 32 + l15) * NN + 8 * l4;
    const unsigned short* vp01 = vp00 + 32;
    const unsigned short* vp10 = vp00 + 16 * NN;
    const unsigned short* vp11 = vp10 + 32;

    const int srow  = w * 8 + (lane >> 3);
    const int sa    = lane & 7;
    const int scol0 = (8 * sa) ^ (4 * (srow & 7));
    float m_reg = -INFINITY, l_reg = 0.f;

    f4 acc[4][2] = {};   // [qgi][cgi]

    bh8 kf = *reinterpret_cast<const bh8*>(kptr);

    for (int tt = 0; tt < NN / KBLK; ++tt) {
        // ---- QK^T ----
        f4 z = {0.f, 0.f, 0.f, 0.f};
        f4 s0 = __builtin_amdgcn_mfma_f32_16x16x32_bf16(qf0, kf, z, 0, 0, 0);
        f4 s1 = __builtin_amdgcn_mfma_f32_16x16x32_bf16(qf1, kf, z, 0, 0, 0);
        kptr += KBLK * C8;
        bh8 kf_n = kf;
        if (tt < NN / KBLK - 1) kf_n = *reinterpret_cast<const bh8*>(kptr);

        #pragma unroll
        for (int r = 0; r < 4; ++r) {
            int q0 = qg0 * 16 + l4 * 4 + r;
            int q1 = q0 + 16;
            int kcol = ng * 16 + l15;
            S[q0][kcol ^ (4 * (q0 & 7))] = s0[r];
            S[q1][kcol ^ (4 * (q1 & 7))] = s1[r];
        }
        __syncthreads();   // b1: S complete

        bh8 vf00 = *reinterpret_cast<const bh8*>(vp00);
        bh8 vf01 = *reinterpret_cast<const bh8*>(vp01);
        bh8 vf10 = *reinterpret_cast<const bh8*>(vp10);
        bh8 vf11 = *reinterpret_cast<const bh8*>(vp11);
        vp00 += KBLK; vp01 += KBLK; vp10 += KBLK; vp11 += KBLK;

        // ---- online softmax (8 rows per wave) ----
        f4 sv0 = *reinterpret_cast<const f4*>(&S[srow][scol0]);
        f4 sv1 = *reinterpret_cast<const f4*>(&S[srow][scol0 ^ 4]);
        float tmax = fmaxf(fmaxf(fmaxf(sv0[0], sv0[1]), fmaxf(sv0[2], sv0[3])),
                           fmaxf(fmaxf(sv1[0], sv1[1]), fmaxf(sv1[2], sv1[3])));
        tmax = fmaxf(tmax, __shfl_xor(tmax, 1));
        tmax = fmaxf(tmax, __shfl_xor(tmax, 2));
        tmax = fmaxf(tmax, __shfl_xor(tmax, 4));
        float mn = fmaxf(m_reg, tmax);
        float alpha = __expf(m_reg - mn);
        float p0 = __expf(sv0[0] - mn), p1 = __expf(sv0[1] - mn);
        float p2 = __expf(sv0[2] - mn), p3 = __expf(sv0[3] - mn);
        float p4 = __expf(sv1[0] - mn), p5 = __expf(sv1[1] - mn);
        float p6 = __expf(sv1[2] - mn), p7 = __expf(sv1[3] - mn);
        float rs = ((p0 + p1) + (p2 + p3)) + ((p4 + p5) + (p6 + p7));
        rs += __shfl_xor(rs, 1);
        rs += __shfl_xor(rs, 2);
        rs += __shfl_xor(rs, 4);
        l_reg = l_reg * alpha + rs;
        m_reg = mn;
        if (sa == 0) a_lds[srow] = alpha;
        bh8 pb;
        pb[0] = (short)f2bf(p0); pb[1] = (short)f2bf(p1);
        pb[2] = (short)f2bf(p2); pb[3] = (short)f2bf(p3);
        pb[4] = (short)f2bf(p4); pb[5] = (short)f2bf(p5);
        pb[6] = (short)f2bf(p6); pb[7] = (short)f2bf(p7);
        *reinterpret_cast<bh8*>(&P[tt & 1][srow][(8 * sa) ^ (8 * (srow & 7))]) = pb;
        __syncthreads();   // b2: P + a_lds complete

        // ---- rescale + PV ----
        #pragma unroll
        for (int qgi = 0; qgi < 4; ++qgi) {
            f4 al = *reinterpret_cast<const f4*>(&a_lds[qgi * 16 + l4 * 4]);
            #pragma unroll
            for (int cgi = 0; cgi < 2; ++cgi) {
                acc[qgi][cgi][0] *= al[0];
                acc[qgi][cgi][1] *= al[1];
                acc[qgi][cgi][2] *= al[2];
                acc[qgi][cgi][3] *= al[3];
            }
        }
        const unsigned short* Pb = &P[tt & 1][0][0];
        #pragma unroll
        for (int ks = 0; ks < 2; ++ks) {
            bh8 pa[4];
            #pragma unroll
            for (int qgi = 0; qgi < 4; ++qgi) {
                int q   = qgi * 16 + l15;
                int col = (ks * 32 + 8 * l4) ^ (8 * (q & 7));
                pa[qgi] = *reinterpret_cast<const bh8*>(Pb + q * 64 + col);
            }
            bh8 vfa = ks ? vf01 : vf00;
            bh8 vfb = ks ? vf11 : vf10;
            #pragma unroll
            for (int qgi = 0; qgi < 4; ++qgi)
                acc[qgi][0] = __builtin_amdgcn_mfma_f32_16x16x32_bf16(pa[qgi], vfa, acc[qgi][0], 0, 0, 0);
            #pragma unroll
            for (int qgi = 0; qgi < 4; ++qgi)
                acc[qgi][1] = __builtin_amdgcn_mfma_f32_16x16x32_bf16(pa[qgi], vfb, acc[qgi][1], 0, 0, 0);
        }
        kf = kf_n;
    }

    // ---- epilogue: out = gamma*(acc/l) + x ----
    if (sa == 0) l_lds[srow] = l_reg;
    __syncthreads();
    const float g = gamma[0];
    #pragma unroll
    for (int qgi = 0; qgi < 4; ++qgi) {
        f4 lv = *reinterpret_cast<const f4*>(&l_lds[qgi * 16 + l4 * 4]);
        f4 li;
        li[0] = 1.f / lv[0]; li[1] = 1.f / lv[1];
        li[2] = 1.f / lv[2]; li[3] = 1.f / lv[3];
        #pragma unroll
        for (int cgi = 0; cgi < 2; ++cgi) {
            int c = w * 32 + cgi * 16 + l15;
            size_t idx = ((size_t)(b * CC) + c) * NN + r0 + qgi * 16 + l4 * 4;
            float4 xr = *reinterpret_cast<const float4*>(x + idx);
            float4 o4;
            o4.x = g * (acc[qgi][cgi][0] * li[0]) + xr.x;
            o4.y = g * (acc[qgi][cgi][1] * li[1]) + xr.y;
            o4.z = g * (acc[qgi][cgi][2] * li[2]) + xr.z;
            o4.w = g * (acc[qgi][cgi][3] * li[3]) + xr.w;
            *reinterpret_cast<float4*>(out + idx) = o4;
        }
    }
}

// ---------------------------------------------------------------------------
extern "C" void kernel_launch(void* const* d_in, const int* in_sizes, int n_in,
                              void* d_out, int out_size, void* d_ws, size_t ws_size,
                              hipStream_t stream)
{
    (void)in_sizes; (void)n_in; (void)out_size; (void)ws_size;

    const float* x   = (const float*)d_in[0];
    const float* xe  = (const float*)d_in[1];
    const float* Wq  = (const float*)d_in[2];
    const float* bq  = (const float*)d_in[3];
    const float* Wk  = (const float*)d_in[4];
    const float* bk  = (const float*)d_in[5];
    const float* Wv  = (const float*)d_in[6];
    const float* bv  = (const float*)d_in[7];
    const float* hp  = (const float*)d_in[8];
    const float* wp  = (const float*)d_in[9];
    const float* gam = (const float*)d_in[10];
    float* out = (float*)d_out;

    // workspace: qb bf16 [B][N][32] (1MB) | kb (1MB) | v bf16 [B][C][N] (8MB) | wb bf16 [320][256] (160KB)
    char* ws = (char*)d_ws;
    unsigned short* qb = (unsigned short*)ws;
    unsigned short* kb = (unsigned short*)(ws + (size_t)BB * NN * C8 * 2);
    unsigned short* v  = (unsigned short*)(ws + 2 * (size_t)BB * NN * C8 * 2);
    unsigned short* wbuf = (unsigned short*)(ws + 2 * (size_t)BB * NN * C8 * 2
                                                + (size_t)BB * CC * NN * 2);

    wconv_kernel<<<80, 256, 0, stream>>>(Wq, Wk, Wv, wbuf);
    proj_kernel<<<BB * (NN / 64), 640, 0, stream>>>(x, xe, wbuf, bq, bk, bv, hp, wp, qb, kb, v);
    attn_mfma_kernel<<<BB * (NN / QBLK), 512, 0, stream>>>(qb, kb, v, x, gam, out);
}